// Round 1
// baseline (529.708 us; speedup 1.0000x reference)
//
#include <hip/hip_runtime.h>
#include <hip/hip_bf16.h>
#include <math.h>

#define D_IN   256
#define D_OUT  128
#define DZ     384   // [low | high | mlp] bf16, 768 B per row

typedef __attribute__((ext_vector_type(8))) short short8;
typedef __attribute__((ext_vector_type(4))) float floatx4;

__device__ __forceinline__ unsigned short f2bf(float f) {
  union { float f; unsigned u; } v; v.f = f;
  unsigned r = v.u + 0x7fffu + ((v.u >> 16) & 1u);  // RNE
  return (unsigned short)(r >> 16);
}

// ---------------------------------------------------------------------------
// K0: pack [Wl|Wh|Wm] into MFMA B-fragment order.
// frag f = kt*24+nt holds B[k=kt*32+quad*8+j][n=nt*16+(lane&15)]
// flat index t = f*512 + lane*8 + j.
// ---------------------------------------------------------------------------
__global__ void repack_w_kernel(const float* __restrict__ Wl,
                                const float* __restrict__ Wh,
                                const float* __restrict__ Wm,
                                unsigned short* __restrict__ Bpack) {
  int t = blockIdx.x * 256 + threadIdx.x;  // 0..98303
  int j = t & 7;
  int lane = (t >> 3) & 63;
  int f = t >> 9;          // 0..191
  int nt = f % 24, kt = f / 24;
  int k = kt * 32 + (lane >> 4) * 8 + j;
  int n = nt * 16 + (lane & 15);
  const float* W = (n < 128) ? Wl : (n < 256 ? Wh : Wm);
  Bpack[t] = f2bf(W[k * D_OUT + (n & 127)]);
}

// ---------------------------------------------------------------------------
// K1: Z = x @ [Wl|Wh|Wm], bf16 MFMA, f32->bf16 convert fused into the A-load
// via v_cvt_pk_bf16_f32 (RNE, bit-identical to f2bf -> Z unchanged).
// 512-thr block = 8 waves over the same 64 rows; wave w owns ctiles
// w*3..w*3+2 (acc 4 strips x 3 ctiles = 48 AGPR). launch_bounds(512,4)
// -> 2 blocks/CU -> 4 waves/SIMD. A shared across 8 waves via L1;
// B (192 KB) is XCD-L2-resident. LDS-staged epilogue, 16B coalesced stores.
// ---------------------------------------------------------------------------
#define LDSROW 392  // shorts/row: 784 B (16B-aligned); 4-row stride = 16 mod 32
__global__ __launch_bounds__(512, 4) void gemm_kernel(
    const float* __restrict__ x,
    const unsigned short* __restrict__ Bpack, unsigned short* __restrict__ Z,
    int n_nodes) {
  __shared__ unsigned short tile[64 * LDSROW];
  const int lane = threadIdx.x & 63;
  const int w = threadIdx.x >> 6;  // 0..7: column group (3 ctiles)
  const int rowbase = blockIdx.x * 64;
  const int m16 = lane & 15, quad = lane >> 4;

  floatx4 acc[4][3];
#pragma unroll
  for (int s = 0; s < 4; s++)
#pragma unroll
    for (int c = 0; c < 3; c++) acc[s][c] = (floatx4)(0.f);

  const float4* xr[4];
#pragma unroll
  for (int s = 0; s < 4; s++) {
    int r = rowbase + s * 16 + m16;
    if (r > n_nodes - 1) r = n_nodes - 1;  // clamp; stores are guarded
    // row*256 floats /4 + col base (quad*8 floats = 2 float4)
    xr[s] = (const float4*)x + (size_t)r * 64 + quad * 2;
  }
  const short8* bp = (const short8*)Bpack + lane;

#pragma unroll
  for (int kt = 0; kt < 8; kt++) {
    short8 a[4];
#pragma unroll
    for (int s = 0; s < 4; s++) {
      float4 f0 = xr[s][kt * 8];
      float4 f1 = xr[s][kt * 8 + 1];
      unsigned w0, w1, w2, w3;
      asm("v_cvt_pk_bf16_f32 %0, %1, %2" : "=v"(w0) : "v"(f0.x), "v"(f0.y));
      asm("v_cvt_pk_bf16_f32 %0, %1, %2" : "=v"(w1) : "v"(f0.z), "v"(f0.w));
      asm("v_cvt_pk_bf16_f32 %0, %1, %2" : "=v"(w2) : "v"(f1.x), "v"(f1.y));
      asm("v_cvt_pk_bf16_f32 %0, %1, %2" : "=v"(w3) : "v"(f1.z), "v"(f1.w));
      union { uint4 u; short8 s8; } cv;
      cv.u = make_uint4(w0, w1, w2, w3);
      a[s] = cv.s8;
    }
#pragma unroll
    for (int c = 0; c < 3; c++) {
      short8 b = bp[(kt * 24 + w * 3 + c) * 64];
#pragma unroll
      for (int s = 0; s < 4; s++)
        acc[s][c] =
            __builtin_amdgcn_mfma_f32_16x16x32_bf16(a[s], b, acc[s][c], 0, 0, 0);
    }
  }

  // stage to LDS in C-layout (row = s*16+quad*4+r, col = (w*3+c)*16+m16)
#pragma unroll
  for (int s = 0; s < 4; s++)
#pragma unroll
    for (int c = 0; c < 3; c++)
#pragma unroll
      for (int r = 0; r < 4; r++)
        tile[(s * 16 + quad * 4 + r) * LDSROW + (w * 3 + c) * 16 + m16] =
            f2bf(acc[s][c][r]);
  __syncthreads();

  // coalesced store: 64 rows x 48 chunks of 16B = 3072 chunks / 512 thr
#pragma unroll
  for (int it = 0; it < 6; it++) {
    int chunk = it * 512 + threadIdx.x;
    int row = chunk / 48, col = (chunk % 48) * 8;
    int grow = rowbase + row;
    if (grow < n_nodes)
      *(short8*)(Z + (size_t)grow * DZ + col) =
          *(const short8*)&tile[row * LDSROW + col];
  }
}

// ---------------------------------------------------------------------------
// CSR build, rank-based (single atomic pass):
//   rank_kernel: rank[e] = atomicAdd(cnt[dst],1)   (only atomics in pipeline)
//   scan1/2/3 : exclusive scan of cnt -> rowptr (+ rowptr[N]=E)
//   scatter   : meta[rowptr[dst]+rank[e]] = {src, bf16(wl)|bf16(wh)<<16}
// ---------------------------------------------------------------------------
__global__ void rank_kernel(const int* __restrict__ dst, int* __restrict__ cnt,
                            int* __restrict__ rank, int E) {
  int e = (blockIdx.x * 256 + threadIdx.x) * 4;
  if (e + 3 < E) {
    int4 d = *(const int4*)&dst[e];
    int r0 = atomicAdd(&cnt[d.x], 1);
    int r1 = atomicAdd(&cnt[d.y], 1);
    int r2 = atomicAdd(&cnt[d.z], 1);
    int r3 = atomicAdd(&cnt[d.w], 1);
    *(int4*)&rank[e] = make_int4(r0, r1, r2, r3);
  } else {
    for (int k = e; k < E; k++) rank[k] = atomicAdd(&cnt[dst[k]], 1);
  }
}

__global__ __launch_bounds__(256) void scan1_kernel(
    const int* __restrict__ cnt, int* __restrict__ rowptr,
    int* __restrict__ bsum, int n) {
  __shared__ int sd[256];
  int t = threadIdx.x;
  int base = blockIdx.x * 1024 + t * 4;
  int v0 = base + 0 < n ? cnt[base + 0] : 0;
  int v1 = base + 1 < n ? cnt[base + 1] : 0;
  int v2 = base + 2 < n ? cnt[base + 2] : 0;
  int v3 = base + 3 < n ? cnt[base + 3] : 0;
  int tsum = v0 + v1 + v2 + v3;
  sd[t] = tsum;
  __syncthreads();
  for (int off = 1; off < 256; off <<= 1) {
    int add = (t >= off) ? sd[t - off] : 0;
    __syncthreads();
    sd[t] += add;
    __syncthreads();
  }
  int excl = sd[t] - tsum;
  if (base + 0 < n) rowptr[base + 0] = excl;
  if (base + 1 < n) rowptr[base + 1] = excl + v0;
  if (base + 2 < n) rowptr[base + 2] = excl + v0 + v1;
  if (base + 3 < n) rowptr[base + 3] = excl + v0 + v1 + v2;
  if (t == 255) bsum[blockIdx.x] = sd[255];
}

__global__ __launch_bounds__(128) void scan2_kernel(int* __restrict__ bsum,
                                                    int nb) {
  __shared__ int sd[128];
  int t = threadIdx.x;
  int v = t < nb ? bsum[t] : 0;
  sd[t] = v;
  __syncthreads();
  for (int off = 1; off < 128; off <<= 1) {
    int add = (t >= off) ? sd[t - off] : 0;
    __syncthreads();
    sd[t] += add;
    __syncthreads();
  }
  if (t < nb) bsum[t] = sd[t] - v;  // exclusive
}

__global__ void scan3_kernel(int* __restrict__ rowptr,
                             const int* __restrict__ bsum, int n, int E) {
  int i = blockIdx.x * 256 + threadIdx.x;
  if (i < n) {
    rowptr[i] = rowptr[i] + bsum[i >> 10];
    if (i == 0) rowptr[n] = E;
  }
}

__global__ void scatter_kernel(const int* __restrict__ src,
                               const int* __restrict__ dst,
                               const float* __restrict__ wlo,
                               const float* __restrict__ whi,
                               const int* __restrict__ rowptr,
                               const int* __restrict__ rank,
                               uint2* __restrict__ meta, int E) {
  int e = blockIdx.x * 256 + threadIdx.x;
  if (e < E) {
    int d = dst[e];
    int pos = rowptr[d] + rank[e];
    unsigned wl = f2bf(wlo[e]), wh = f2bf(whi[e]);
    meta[pos] = make_uint2((unsigned)src[e], wl | (wh << 16));
  }
}

// ---------------------------------------------------------------------------
// K_node: CSR gather + relu + attention3. 128-thr blocks = 2 independent
// waves = 2 nodes. readfirstlane(node) -> rowptr/meta via scalar loads.
// Lane layout (NEW): 16B loads, 32 lanes cover one edge's 512B [low|high]
// row, so each wave processes TWO edges per load instruction:
//   g      = lane>>5        edge group (even/odd edge of a pair)
//   isHigh = (lane>>4)&1    low dims (0) / high dims (1)
//   d16    = lane&15        dim block: 8 dims d16*8..d16*8+7
// Halves gather VMEM instrs + per-edge address VALU vs the 8B version.
// ---------------------------------------------------------------------------
__global__ __launch_bounds__(128) void node_kernel(
    const unsigned short* __restrict__ Zh, const int* __restrict__ rowptr,
    const uint2* __restrict__ meta, const float* __restrict__ a_low,
    const float* __restrict__ a_high, const float* __restrict__ a_mlp,
    const float* __restrict__ att_vec, float* __restrict__ out, int n_nodes) {
  int node = blockIdx.x * 2 + (threadIdx.x >> 6);
  if (node >= n_nodes) return;
  node = __builtin_amdgcn_readfirstlane(node);  // wave-uniform -> s_loads
  const int lane = threadIdx.x & 63;
  const int g = lane >> 5;             // edge group within a pair
  const int isHigh = (lane >> 4) & 1;  // dim half
  const int d16 = lane & 15;           // 8-dim block index
  const int zoff = (lane & 31) * 16;   // byte offset into [low|high] 512B
  const char* Zb = (const char*)Zh;

  const int start = rowptr[node];
  const int end = rowptr[node + 1];

  float a0 = 0.f, a1 = 0.f, a2 = 0.f, a3 = 0.f;
  float a4 = 0.f, a5 = 0.f, a6 = 0.f, a7 = 0.f;
  auto step8 = [&](uint4 z, float wv) {
    a0 += wv * __uint_as_float(z.x << 16);
    a1 += wv * __uint_as_float(z.x & 0xffff0000u);
    a2 += wv * __uint_as_float(z.y << 16);
    a3 += wv * __uint_as_float(z.y & 0xffff0000u);
    a4 += wv * __uint_as_float(z.z << 16);
    a5 += wv * __uint_as_float(z.z & 0xffff0000u);
    a6 += wv * __uint_as_float(z.w << 16);
    a7 += wv * __uint_as_float(z.w & 0xffff0000u);
  };

  int j = start;
  const int nfull = (end - start) & ~7;
  for (; j < start + nfull; j += 8) {  // 8 edges = 4 pairs per iter
    uint2 m[8];
#pragma unroll
    for (int u = 0; u < 8; u++) m[u] = meta[j + u];  // wave-uniform s_loads
    uint4 z[4];
    float wv[4];
#pragma unroll
    for (int p = 0; p < 4; p++) {
      unsigned sx = g ? m[2 * p + 1].x : m[2 * p].x;
      unsigned wy = g ? m[2 * p + 1].y : m[2 * p].y;
      z[p] = *(const uint4*)(Zb + (size_t)sx * 768 + zoff);
      wv[p] = __uint_as_float(isHigh ? (wy & 0xffff0000u) : (wy << 16));
    }
#pragma unroll
    for (int p = 0; p < 4; p++) step8(z[p], wv[p]);
  }
  for (; j < end; j += 2) {  // tail: pairs, odd-edge lanes predicated
    uint2 mA = meta[j];
    uint2 mB = meta[(j + 1 < end) ? j + 1 : j];
    unsigned sx = g ? mB.x : mA.x;
    unsigned wy = g ? mB.y : mA.y;
    float wv = __uint_as_float(isHigh ? (wy & 0xffff0000u) : (wy << 16));
    if (g && (j + 1 >= end)) wv = 0.f;
    uint4 zz = *(const uint4*)(Zb + (size_t)sx * 768 + zoff);
    step8(zz, wv);
  }

  // combine even/odd edge-group partial sums
  a0 += __shfl_xor(a0, 32); a1 += __shfl_xor(a1, 32);
  a2 += __shfl_xor(a2, 32); a3 += __shfl_xor(a3, 32);
  a4 += __shfl_xor(a4, 32); a5 += __shfl_xor(a5, 32);
  a6 += __shfl_xor(a6, 32); a7 += __shfl_xor(a7, 32);

  float h0 = fmaxf(a0, 0.f), h1 = fmaxf(a1, 0.f);
  float h2 = fmaxf(a2, 0.f), h3 = fmaxf(a3, 0.f);
  float h4 = fmaxf(a4, 0.f), h5 = fmaxf(a5, 0.f);
  float h6 = fmaxf(a6, 0.f), h7 = fmaxf(a7, 0.f);

  // mlp branch (own node), dims d16*8..+7
  uint4 zm = *(const uint4*)(Zb + (size_t)node * 768 + 512 + (size_t)d16 * 16);
  float q0 = fmaxf(__uint_as_float(zm.x << 16), 0.f);
  float q1 = fmaxf(__uint_as_float(zm.x & 0xffff0000u), 0.f);
  float q2 = fmaxf(__uint_as_float(zm.y << 16), 0.f);
  float q3 = fmaxf(__uint_as_float(zm.y & 0xffff0000u), 0.f);
  float q4 = fmaxf(__uint_as_float(zm.z << 16), 0.f);
  float q5 = fmaxf(__uint_as_float(zm.z & 0xffff0000u), 0.f);
  float q6 = fmaxf(__uint_as_float(zm.w << 16), 0.f);
  float q7 = fmaxf(__uint_as_float(zm.w & 0xffff0000u), 0.f);

  const float* av_b = isHigh ? a_high : a_low;
  float4 ab0 = *(const float4*)&av_b[d16 * 8];
  float4 ab1 = *(const float4*)&av_b[d16 * 8 + 4];
  float4 am0 = *(const float4*)&a_mlp[d16 * 8];
  float4 am1 = *(const float4*)&a_mlp[d16 * 8 + 4];
  float v1 = h0 * ab0.x + h1 * ab0.y + h2 * ab0.z + h3 * ab0.w +
             h4 * ab1.x + h5 * ab1.y + h6 * ab1.z + h7 * ab1.w;
  float v2 = isHigh ? 0.f
                    : (q0 * am0.x + q1 * am0.y + q2 * am0.z + q3 * am0.w +
                       q4 * am1.x + q5 * am1.y + q6 * am1.z + q7 * am1.w);
  // 16-lane butterfly: lanes 0-15 = low score, 16-31 = high score
#pragma unroll
  for (int off = 1; off < 16; off <<= 1) {
    v1 += __shfl_xor(v1, off);
    v2 += __shfl_xor(v2, off);
  }
  float s_lo = __shfl(v1, 0);
  float s_hi = __shfl(v1, 16);
  float s_ml = __shfl(v2, 0);

  float g0 = 1.f / (1.f + __expf(-s_lo));
  float g1 = 1.f / (1.f + __expf(-s_hi));
  float g2 = 1.f / (1.f + __expf(-s_ml));
  const float inv3 = 1.f / 3.f;
  float m0 = (g0 * att_vec[0] + g1 * att_vec[3] + g2 * att_vec[6]) * inv3;
  float m1 = (g0 * att_vec[1] + g1 * att_vec[4] + g2 * att_vec[7]) * inv3;
  float m2 = (g0 * att_vec[2] + g1 * att_vec[5] + g2 * att_vec[8]) * inv3;
  float mx = fmaxf(m0, fmaxf(m1, m2));
  float e0 = __expf(m0 - mx), e1 = __expf(m1 - mx), e2 = __expf(m2 - mx);
  float inv = 1.f / (e0 + e1 + e2);
  float c0 = 3.f * inv * e0, c1 = 3.f * inv * e1, c2 = 3.f * inv * e2;

  // low lanes fetch matching-high dims from lane+16
  float hh0 = __shfl_xor(h0, 16), hh1 = __shfl_xor(h1, 16);
  float hh2 = __shfl_xor(h2, 16), hh3 = __shfl_xor(h3, 16);
  float hh4 = __shfl_xor(h4, 16), hh5 = __shfl_xor(h5, 16);
  float hh6 = __shfl_xor(h6, 16), hh7 = __shfl_xor(h7, 16);

  if ((lane >> 4) == 0) {  // lanes 0-15 write the full 512B row
    float4 o0, o1;
    o0.x = c0 * h0 + c1 * hh0 + c2 * q0;
    o0.y = c0 * h1 + c1 * hh1 + c2 * q1;
    o0.z = c0 * h2 + c1 * hh2 + c2 * q2;
    o0.w = c0 * h3 + c1 * hh3 + c2 * q3;
    o1.x = c0 * h4 + c1 * hh4 + c2 * q4;
    o1.y = c0 * h5 + c1 * hh5 + c2 * q5;
    o1.z = c0 * h6 + c1 * hh6 + c2 * q6;
    o1.w = c0 * h7 + c1 * hh7 + c2 * q7;
    *(float4*)&out[(size_t)node * D_OUT + d16 * 8] = o0;
    *(float4*)&out[(size_t)node * D_OUT + d16 * 8 + 4] = o1;
  }
}

// ---------------------------------------------------------------------------
extern "C" void kernel_launch(void* const* d_in, const int* in_sizes, int n_in,
                              void* d_out, int out_size, void* d_ws,
                              size_t ws_size, hipStream_t stream) {
  const float* x    = (const float*)d_in[0];
  const int*   esrc = (const int*)d_in[1];
  const int*   edst = (const int*)d_in[2];
  const float* wlo  = (const float*)d_in[3];
  const float* whi  = (const float*)d_in[4];
  const float* Wl   = (const float*)d_in[6];
  const float* Wh   = (const float*)d_in[7];
  const float* Wm   = (const float*)d_in[8];
  const float* alo  = (const float*)d_in[9];
  const float* ahi  = (const float*)d_in[10];
  const float* amlp = (const float*)d_in[11];
  const float* av   = (const float*)d_in[12];
  float* out = (float*)d_out;

  const int N = in_sizes[0] / D_IN;  // 100000
  const int E = in_sizes[1];         // 1600000

  char* ws = (char*)d_ws;
  size_t off = 0;
  auto carve = [&](size_t bytes) -> void* {
    void* p = ws + off;
    off = (off + bytes + 255) & ~(size_t)255;
    return p;
  };
  unsigned short* Z     = (unsigned short*)carve((size_t)N * DZ * 2);
  unsigned short* Bpack = (unsigned short*)carve(98304 * 2);
  int*   cnt    = (int*)carve((size_t)N * 4);
  int*   rowptr = (int*)carve((size_t)(N + 1) * 4);
  int*   rank   = (int*)carve((size_t)E * 4);
  int*   bsum   = (int*)carve(128 * 4);
  uint2* meta   = (uint2*)carve((size_t)E * 8);

  repack_w_kernel<<<384, 256, 0, stream>>>(Wl, Wh, Wm, Bpack);

  // CSR build (independent of gemm)
  hipMemsetAsync(cnt, 0, (size_t)N * 4, stream);
  rank_kernel<<<(E / 4 + 255) / 256, 256, 0, stream>>>(edst, cnt, rank, E);
  int nb = (N + 1023) / 1024;
  scan1_kernel<<<nb, 256, 0, stream>>>(cnt, rowptr, bsum, N);
  scan2_kernel<<<1, 128, 0, stream>>>(bsum, nb);
  scan3_kernel<<<(N + 255) / 256, 256, 0, stream>>>(rowptr, bsum, N, E);
  scatter_kernel<<<(E + 255) / 256, 256, 0, stream>>>(esrc, edst, wlo, whi,
                                                      rowptr, rank, meta, E);

  gemm_kernel<<<(N + 63) / 64, 512, 0, stream>>>(x, Bpack, Z, N);

  node_kernel<<<(N + 1) / 2, 128, 0, stream>>>(Z, rowptr, meta, alo, ahi, amlp,
                                               av, out, N);
}

// Round 2
// 510.920 us; speedup vs baseline: 1.0368x; 1.0368x over previous
//
#include <hip/hip_runtime.h>
#include <hip/hip_bf16.h>
#include <math.h>

#define D_IN   256
#define D_OUT  128
#define DZ     384   // [low | high | mlp] bf16, 768 B per row

typedef __attribute__((ext_vector_type(8))) short short8;
typedef __attribute__((ext_vector_type(4))) float floatx4;

__device__ __forceinline__ unsigned short f2bf(float f) {
  union { float f; unsigned u; } v; v.f = f;
  unsigned r = v.u + 0x7fffu + ((v.u >> 16) & 1u);  // RNE
  return (unsigned short)(r >> 16);
}

// ---------------------------------------------------------------------------
// K0: pack [Wl|Wh|Wm] into MFMA B-fragment order.
// frag f = kt*24+nt holds B[k=kt*32+quad*8+j][n=nt*16+(lane&15)]
// flat index t = f*512 + lane*8 + j.
// ---------------------------------------------------------------------------
__global__ void repack_w_kernel(const float* __restrict__ Wl,
                                const float* __restrict__ Wh,
                                const float* __restrict__ Wm,
                                unsigned short* __restrict__ Bpack) {
  int t = blockIdx.x * 256 + threadIdx.x;  // 0..98303
  int j = t & 7;
  int lane = (t >> 3) & 63;
  int f = t >> 9;          // 0..191
  int nt = f % 24, kt = f / 24;
  int k = kt * 32 + (lane >> 4) * 8 + j;
  int n = nt * 16 + (lane & 15);
  const float* W = (n < 128) ? Wl : (n < 256 ? Wh : Wm);
  Bpack[t] = f2bf(W[k * D_OUT + (n & 127)]);
}

// ---------------------------------------------------------------------------
// K0b: x (fp32) -> xb (bf16), 8 elems/thread, 16B stores.
// (Reinstated: fusing the cvt into the GEMM A-gather was latency-bound —
//  round-1 gemm hit 137us at MfmaUtil 5.5%. Streaming cvt + bf16 gather wins.)
// ---------------------------------------------------------------------------
__global__ void xcvt_kernel(const float* __restrict__ x,
                            unsigned short* __restrict__ xb, int n8) {
  int i = blockIdx.x * 256 + threadIdx.x;
  if (i < n8) {
    const float4* p = (const float4*)x + (size_t)i * 2;
    float4 f0 = p[0], f1 = p[1];
    short8 o;
    o[0] = (short)f2bf(f0.x); o[1] = (short)f2bf(f0.y);
    o[2] = (short)f2bf(f0.z); o[3] = (short)f2bf(f0.w);
    o[4] = (short)f2bf(f1.x); o[5] = (short)f2bf(f1.y);
    o[6] = (short)f2bf(f1.z); o[7] = (short)f2bf(f1.w);
    ((short8*)xb)[i] = o;
  }
}

// ---------------------------------------------------------------------------
// K1: Z = xb @ [Wl|Wh|Wm], bf16 MFMA. 512-thr block = 8 waves over the same
// 64 rows; wave w owns ctiles w*3..w*3+2 (acc 4 strips x 3 ctiles = 48 AGPR).
// launch_bounds(512,4) -> 2 blocks/CU -> 4 waves/SIMD for latency hiding.
// A-strip loads use compile-time offsets; A shared across 8 waves via L1;
// B (192 KB) is XCD-L2-resident. LDS-staged epilogue, 16B coalesced stores.
// ---------------------------------------------------------------------------
#define LDSROW 392  // shorts/row: 784 B (16B-aligned); 4-row stride = 16 mod 32
__global__ __launch_bounds__(512, 4) void gemm_kernel(
    const unsigned short* __restrict__ xb,
    const unsigned short* __restrict__ Bpack, unsigned short* __restrict__ Z,
    int n_nodes) {
  __shared__ unsigned short tile[64 * LDSROW];
  const int lane = threadIdx.x & 63;
  const int w = threadIdx.x >> 6;  // 0..7: column group (3 ctiles)
  const int rowbase = blockIdx.x * 64;
  const int m16 = lane & 15, quad = lane >> 4;

  floatx4 acc[4][3];
#pragma unroll
  for (int s = 0; s < 4; s++)
#pragma unroll
    for (int c = 0; c < 3; c++) acc[s][c] = (floatx4)(0.f);

  const short8* xr[4];
#pragma unroll
  for (int s = 0; s < 4; s++) {
    int r = rowbase + s * 16 + m16;
    if (r > n_nodes - 1) r = n_nodes - 1;  // clamp; stores are guarded
    xr[s] = (const short8*)xb + (size_t)r * 32 + quad;  // row*256/8 + quad
  }
  const short8* bp = (const short8*)Bpack + lane;

#pragma unroll
  for (int kt = 0; kt < 8; kt++) {
    short8 a[4];
#pragma unroll
    for (int s = 0; s < 4; s++) a[s] = xr[s][kt * 4];
#pragma unroll
    for (int c = 0; c < 3; c++) {
      short8 b = bp[(kt * 24 + w * 3 + c) * 64];
#pragma unroll
      for (int s = 0; s < 4; s++)
        acc[s][c] =
            __builtin_amdgcn_mfma_f32_16x16x32_bf16(a[s], b, acc[s][c], 0, 0, 0);
    }
  }

  // stage to LDS in C-layout (row = s*16+quad*4+r, col = (w*3+c)*16+m16)
#pragma unroll
  for (int s = 0; s < 4; s++)
#pragma unroll
    for (int c = 0; c < 3; c++)
#pragma unroll
      for (int r = 0; r < 4; r++)
        tile[(s * 16 + quad * 4 + r) * LDSROW + (w * 3 + c) * 16 + m16] =
            f2bf(acc[s][c][r]);
  __syncthreads();

  // coalesced store: 64 rows x 48 chunks of 16B = 3072 chunks / 512 thr
#pragma unroll
  for (int it = 0; it < 6; it++) {
    int chunk = it * 512 + threadIdx.x;
    int row = chunk / 48, col = (chunk % 48) * 8;
    int grow = rowbase + row;
    if (grow < n_nodes)
      *(short8*)(Z + (size_t)grow * DZ + col) =
          *(const short8*)&tile[row * LDSROW + col];
  }
}

// ---------------------------------------------------------------------------
// CSR build, rank-based (single atomic pass):
//   rank_kernel: rank[e] = atomicAdd(cnt[dst],1)   (only atomics in pipeline)
//   scan1/2/3 : exclusive scan of cnt -> rowptr (+ rowptr[N]=E)
//   scatter   : meta[rowptr[dst]+rank[e]] = {src, bf16(wl)|bf16(wh)<<16}
// ---------------------------------------------------------------------------
__global__ void rank_kernel(const int* __restrict__ dst, int* __restrict__ cnt,
                            int* __restrict__ rank, int E) {
  int e = (blockIdx.x * 256 + threadIdx.x) * 4;
  if (e + 3 < E) {
    int4 d = *(const int4*)&dst[e];
    int r0 = atomicAdd(&cnt[d.x], 1);
    int r1 = atomicAdd(&cnt[d.y], 1);
    int r2 = atomicAdd(&cnt[d.z], 1);
    int r3 = atomicAdd(&cnt[d.w], 1);
    *(int4*)&rank[e] = make_int4(r0, r1, r2, r3);
  } else {
    for (int k = e; k < E; k++) rank[k] = atomicAdd(&cnt[dst[k]], 1);
  }
}

__global__ __launch_bounds__(256) void scan1_kernel(
    const int* __restrict__ cnt, int* __restrict__ rowptr,
    int* __restrict__ bsum, int n) {
  __shared__ int sd[256];
  int t = threadIdx.x;
  int base = blockIdx.x * 1024 + t * 4;
  int v0 = base + 0 < n ? cnt[base + 0] : 0;
  int v1 = base + 1 < n ? cnt[base + 1] : 0;
  int v2 = base + 2 < n ? cnt[base + 2] : 0;
  int v3 = base + 3 < n ? cnt[base + 3] : 0;
  int tsum = v0 + v1 + v2 + v3;
  sd[t] = tsum;
  __syncthreads();
  for (int off = 1; off < 256; off <<= 1) {
    int add = (t >= off) ? sd[t - off] : 0;
    __syncthreads();
    sd[t] += add;
    __syncthreads();
  }
  int excl = sd[t] - tsum;
  if (base + 0 < n) rowptr[base + 0] = excl;
  if (base + 1 < n) rowptr[base + 1] = excl + v0;
  if (base + 2 < n) rowptr[base + 2] = excl + v0 + v1;
  if (base + 3 < n) rowptr[base + 3] = excl + v0 + v1 + v2;
  if (t == 255) bsum[blockIdx.x] = sd[255];
}

__global__ __launch_bounds__(128) void scan2_kernel(int* __restrict__ bsum,
                                                    int nb) {
  __shared__ int sd[128];
  int t = threadIdx.x;
  int v = t < nb ? bsum[t] : 0;
  sd[t] = v;
  __syncthreads();
  for (int off = 1; off < 128; off <<= 1) {
    int add = (t >= off) ? sd[t - off] : 0;
    __syncthreads();
    sd[t] += add;
    __syncthreads();
  }
  if (t < nb) bsum[t] = sd[t] - v;  // exclusive
}

__global__ void scan3_kernel(int* __restrict__ rowptr,
                             const int* __restrict__ bsum, int n, int E) {
  int i = blockIdx.x * 256 + threadIdx.x;
  if (i < n) {
    rowptr[i] = rowptr[i] + bsum[i >> 10];
    if (i == 0) rowptr[n] = E;
  }
}

__global__ void scatter_kernel(const int* __restrict__ src,
                               const int* __restrict__ dst,
                               const float* __restrict__ wlo,
                               const float* __restrict__ whi,
                               const int* __restrict__ rowptr,
                               const int* __restrict__ rank,
                               uint2* __restrict__ meta, int E) {
  int e = blockIdx.x * 256 + threadIdx.x;
  if (e < E) {
    int d = dst[e];
    int pos = rowptr[d] + rank[e];
    unsigned wl = f2bf(wlo[e]), wh = f2bf(whi[e]);
    meta[pos] = make_uint2((unsigned)src[e], wl | (wh << 16));
  }
}

// ---------------------------------------------------------------------------
// K_node: CSR gather + relu + attention3. 128-thr blocks = 2 independent
// waves = 2 nodes. readfirstlane(node) -> rowptr/meta via scalar loads.
// Lane layout: 16B loads, 32 lanes cover one edge's 512B [low|high] row,
// so each wave processes TWO edges per load instruction:
//   g      = lane>>5        edge group (even/odd edge of a pair)
//   isHigh = (lane>>4)&1    low dims (0) / high dims (1)
//   d16    = lane&15        dim block: 8 dims d16*8..d16*8+7
// ---------------------------------------------------------------------------
__global__ __launch_bounds__(128) void node_kernel(
    const unsigned short* __restrict__ Zh, const int* __restrict__ rowptr,
    const uint2* __restrict__ meta, const float* __restrict__ a_low,
    const float* __restrict__ a_high, const float* __restrict__ a_mlp,
    const float* __restrict__ att_vec, float* __restrict__ out, int n_nodes) {
  int node = blockIdx.x * 2 + (threadIdx.x >> 6);
  if (node >= n_nodes) return;
  node = __builtin_amdgcn_readfirstlane(node);  // wave-uniform -> s_loads
  const int lane = threadIdx.x & 63;
  const int g = lane >> 5;             // edge group within a pair
  const int isHigh = (lane >> 4) & 1;  // dim half
  const int d16 = lane & 15;           // 8-dim block index
  const int zoff = (lane & 31) * 16;   // byte offset into [low|high] 512B
  const char* Zb = (const char*)Zh;

  const int start = rowptr[node];
  const int end = rowptr[node + 1];

  float a0 = 0.f, a1 = 0.f, a2 = 0.f, a3 = 0.f;
  float a4 = 0.f, a5 = 0.f, a6 = 0.f, a7 = 0.f;
  auto step8 = [&](uint4 z, float wv) {
    a0 += wv * __uint_as_float(z.x << 16);
    a1 += wv * __uint_as_float(z.x & 0xffff0000u);
    a2 += wv * __uint_as_float(z.y << 16);
    a3 += wv * __uint_as_float(z.y & 0xffff0000u);
    a4 += wv * __uint_as_float(z.z << 16);
    a5 += wv * __uint_as_float(z.z & 0xffff0000u);
    a6 += wv * __uint_as_float(z.w << 16);
    a7 += wv * __uint_as_float(z.w & 0xffff0000u);
  };

  int j = start;
  const int nfull = (end - start) & ~7;
  for (; j < start + nfull; j += 8) {  // 8 edges = 4 pairs per iter
    uint2 m[8];
#pragma unroll
    for (int u = 0; u < 8; u++) m[u] = meta[j + u];  // wave-uniform s_loads
    uint4 z[4];
    float wv[4];
#pragma unroll
    for (int p = 0; p < 4; p++) {
      unsigned sx = g ? m[2 * p + 1].x : m[2 * p].x;
      unsigned wy = g ? m[2 * p + 1].y : m[2 * p].y;
      z[p] = *(const uint4*)(Zb + (size_t)sx * 768 + zoff);
      wv[p] = __uint_as_float(isHigh ? (wy & 0xffff0000u) : (wy << 16));
    }
#pragma unroll
    for (int p = 0; p < 4; p++) step8(z[p], wv[p]);
  }
  for (; j < end; j += 2) {  // tail: pairs, odd-edge lanes predicated
    uint2 mA = meta[j];
    uint2 mB = meta[(j + 1 < end) ? j + 1 : j];
    unsigned sx = g ? mB.x : mA.x;
    unsigned wy = g ? mB.y : mA.y;
    float wv = __uint_as_float(isHigh ? (wy & 0xffff0000u) : (wy << 16));
    if (g && (j + 1 >= end)) wv = 0.f;
    uint4 zz = *(const uint4*)(Zb + (size_t)sx * 768 + zoff);
    step8(zz, wv);
  }

  // combine even/odd edge-group partial sums
  a0 += __shfl_xor(a0, 32); a1 += __shfl_xor(a1, 32);
  a2 += __shfl_xor(a2, 32); a3 += __shfl_xor(a3, 32);
  a4 += __shfl_xor(a4, 32); a5 += __shfl_xor(a5, 32);
  a6 += __shfl_xor(a6, 32); a7 += __shfl_xor(a7, 32);

  float h0 = fmaxf(a0, 0.f), h1 = fmaxf(a1, 0.f);
  float h2 = fmaxf(a2, 0.f), h3 = fmaxf(a3, 0.f);
  float h4 = fmaxf(a4, 0.f), h5 = fmaxf(a5, 0.f);
  float h6 = fmaxf(a6, 0.f), h7 = fmaxf(a7, 0.f);

  // mlp branch (own node), dims d16*8..+7
  uint4 zm = *(const uint4*)(Zb + (size_t)node * 768 + 512 + (size_t)d16 * 16);
  float q0 = fmaxf(__uint_as_float(zm.x << 16), 0.f);
  float q1 = fmaxf(__uint_as_float(zm.x & 0xffff0000u), 0.f);
  float q2 = fmaxf(__uint_as_float(zm.y << 16), 0.f);
  float q3 = fmaxf(__uint_as_float(zm.y & 0xffff0000u), 0.f);
  float q4 = fmaxf(__uint_as_float(zm.z << 16), 0.f);
  float q5 = fmaxf(__uint_as_float(zm.z & 0xffff0000u), 0.f);
  float q6 = fmaxf(__uint_as_float(zm.w << 16), 0.f);
  float q7 = fmaxf(__uint_as_float(zm.w & 0xffff0000u), 0.f);

  const float* av_b = isHigh ? a_high : a_low;
  float4 ab0 = *(const float4*)&av_b[d16 * 8];
  float4 ab1 = *(const float4*)&av_b[d16 * 8 + 4];
  float4 am0 = *(const float4*)&a_mlp[d16 * 8];
  float4 am1 = *(const float4*)&a_mlp[d16 * 8 + 4];
  float v1 = h0 * ab0.x + h1 * ab0.y + h2 * ab0.z + h3 * ab0.w +
             h4 * ab1.x + h5 * ab1.y + h6 * ab1.z + h7 * ab1.w;
  float v2 = isHigh ? 0.f
                    : (q0 * am0.x + q1 * am0.y + q2 * am0.z + q3 * am0.w +
                       q4 * am1.x + q5 * am1.y + q6 * am1.z + q7 * am1.w);
  // 16-lane butterfly: lanes 0-15 = low score, 16-31 = high score
#pragma unroll
  for (int off = 1; off < 16; off <<= 1) {
    v1 += __shfl_xor(v1, off);
    v2 += __shfl_xor(v2, off);
  }
  float s_lo = __shfl(v1, 0);
  float s_hi = __shfl(v1, 16);
  float s_ml = __shfl(v2, 0);

  float g0 = 1.f / (1.f + __expf(-s_lo));
  float g1 = 1.f / (1.f + __expf(-s_hi));
  float g2 = 1.f / (1.f + __expf(-s_ml));
  const float inv3 = 1.f / 3.f;
  float m0 = (g0 * att_vec[0] + g1 * att_vec[3] + g2 * att_vec[6]) * inv3;
  float m1 = (g0 * att_vec[1] + g1 * att_vec[4] + g2 * att_vec[7]) * inv3;
  float m2 = (g0 * att_vec[2] + g1 * att_vec[5] + g2 * att_vec[8]) * inv3;
  float mx = fmaxf(m0, fmaxf(m1, m2));
  float e0 = __expf(m0 - mx), e1 = __expf(m1 - mx), e2 = __expf(m2 - mx);
  float inv = 1.f / (e0 + e1 + e2);
  float c0 = 3.f * inv * e0, c1 = 3.f * inv * e1, c2 = 3.f * inv * e2;

  // low lanes fetch matching-high dims from lane+16
  float hh0 = __shfl_xor(h0, 16), hh1 = __shfl_xor(h1, 16);
  float hh2 = __shfl_xor(h2, 16), hh3 = __shfl_xor(h3, 16);
  float hh4 = __shfl_xor(h4, 16), hh5 = __shfl_xor(h5, 16);
  float hh6 = __shfl_xor(h6, 16), hh7 = __shfl_xor(h7, 16);

  if ((lane >> 4) == 0) {  // lanes 0-15 write the full 512B row
    float4 o0, o1;
    o0.x = c0 * h0 + c1 * hh0 + c2 * q0;
    o0.y = c0 * h1 + c1 * hh1 + c2 * q1;
    o0.z = c0 * h2 + c1 * hh2 + c2 * q2;
    o0.w = c0 * h3 + c1 * hh3 + c2 * q3;
    o1.x = c0 * h4 + c1 * hh4 + c2 * q4;
    o1.y = c0 * h5 + c1 * hh5 + c2 * q5;
    o1.z = c0 * h6 + c1 * hh6 + c2 * q6;
    o1.w = c0 * h7 + c1 * hh7 + c2 * q7;
    *(float4*)&out[(size_t)node * D_OUT + d16 * 8] = o0;
    *(float4*)&out[(size_t)node * D_OUT + d16 * 8 + 4] = o1;
  }
}

// ---------------------------------------------------------------------------
extern "C" void kernel_launch(void* const* d_in, const int* in_sizes, int n_in,
                              void* d_out, int out_size, void* d_ws,
                              size_t ws_size, hipStream_t stream) {
  const float* x    = (const float*)d_in[0];
  const int*   esrc = (const int*)d_in[1];
  const int*   edst = (const int*)d_in[2];
  const float* wlo  = (const float*)d_in[3];
  const float* whi  = (const float*)d_in[4];
  const float* Wl   = (const float*)d_in[6];
  const float* Wh   = (const float*)d_in[7];
  const float* Wm   = (const float*)d_in[8];
  const float* alo  = (const float*)d_in[9];
  const float* ahi  = (const float*)d_in[10];
  const float* amlp = (const float*)d_in[11];
  const float* av   = (const float*)d_in[12];
  float* out = (float*)d_out;

  const int N = in_sizes[0] / D_IN;  // 100000
  const int E = in_sizes[1];         // 1600000

  char* ws = (char*)d_ws;
  size_t off = 0;
  auto carve = [&](size_t bytes) -> void* {
    void* p = ws + off;
    off = (off + bytes + 255) & ~(size_t)255;
    return p;
  };
  unsigned short* Z     = (unsigned short*)carve((size_t)N * DZ * 2);
  unsigned short* xb    = (unsigned short*)carve((size_t)N * D_IN * 2);
  unsigned short* Bpack = (unsigned short*)carve(98304 * 2);
  int*   cnt    = (int*)carve((size_t)N * 4);
  int*   rowptr = (int*)carve((size_t)(N + 1) * 4);
  int*   rank   = (int*)carve((size_t)E * 4);
  int*   bsum   = (int*)carve(128 * 4);
  uint2* meta   = (uint2*)carve((size_t)E * 8);

  repack_w_kernel<<<384, 256, 0, stream>>>(Wl, Wh, Wm, Bpack);
  int n8 = in_sizes[0] / 8;
  xcvt_kernel<<<(n8 + 255) / 256, 256, 0, stream>>>(x, xb, n8);

  // CSR build (independent of gemm)
  hipMemsetAsync(cnt, 0, (size_t)N * 4, stream);
  rank_kernel<<<(E / 4 + 255) / 256, 256, 0, stream>>>(edst, cnt, rank, E);
  int nb = (N + 1023) / 1024;
  scan1_kernel<<<nb, 256, 0, stream>>>(cnt, rowptr, bsum, N);
  scan2_kernel<<<1, 128, 0, stream>>>(bsum, nb);
  scan3_kernel<<<(N + 255) / 256, 256, 0, stream>>>(rowptr, bsum, N, E);
  scatter_kernel<<<(E + 255) / 256, 256, 0, stream>>>(esrc, edst, wlo, whi,
                                                      rowptr, rank, meta, E);

  gemm_kernel<<<(N + 63) / 64, 512, 0, stream>>>(xb, Bpack, Z, N);

  node_kernel<<<(N + 1) / 2, 128, 0, stream>>>(Z, rowptr, meta, alo, ahi, amlp,
                                               av, out, N);
}